// Round 2
// baseline (343.389 us; speedup 1.0000x reference)
//
#include <hip/hip_runtime.h>

#define E_EDGES 160000
#define N_NODES 10000

// 24^(-0.5)
#define TEMP 0.20412414523193154f

typedef __fp16 half2_t __attribute__((ext_vector_type(2)));
typedef __fp16 half8_t __attribute__((ext_vector_type(8)));
typedef float f32x4 __attribute__((ext_vector_type(4)));

__device__ __forceinline__ float fdot2(half2_t a, half2_t b, float c) {
#if __has_builtin(__builtin_amdgcn_fdot2)
    return __builtin_amdgcn_fdot2(a, b, c, false);
#else
    return fmaf((float)a.x, (float)b.x, fmaf((float)a.y, (float)b.y, c));
#endif
}
__device__ __forceinline__ half2_t pk(float a, float b) {
    return __builtin_amdgcn_cvt_pkrtz(a, b);
}

// W1 LDS swizzle: float4-granule XOR keyed by (row>>3)&3 so the 4 quads
// (rows 8 apart) hit disjoint 16B slots -> no 4-way bank conflict.
// u = row*8 + i4 (float4 linear index); (u>>6)&3 == quad for every row a
// given quad reads (rows quad*8+t and 32+quad*8+t, t<8 -> no carry into bit6).
__device__ __forceinline__ int w1swz(int u) {
    return (u & ~7) | ((u & 7) ^ ((u >> 6) & 3));
}

// prep: W2 [768][64] f32 -> f16 fragment order, AND zero num/den accumulators.
__global__ __launch_bounds__(256)
void prep_kernel(const float* __restrict__ W2, unsigned* __restrict__ w2p,
                 float4* __restrict__ zbuf)
{
    int u = blockIdx.x * blockDim.x + threadIdx.x;   // u < 24576
    // zero num (N*24) + den (N*4) = N*28 floats = 70000 float4
    #pragma unroll
    for (int i = 0; i < 3; ++i) {
        int z = u + i * 24576;
        if (z < (N_NODES * 28) / 4) zbuf[z] = make_float4(0.f, 0.f, 0.f, 0.f);
    }
    int tp    = u & 3;
    int lane  = (u >> 2) & 63;
    int piece = (u >> 8) & 3;
    int c     = u >> 10;
    int em = lane & 15, quad = lane >> 4;
    int row = 32*c + ((piece >> 1) << 4) + em;
    int col = ((piece & 1) << 5) + quad*8 + 2*tp;
    union { half2_t h; unsigned v; } o;
    o.h.x = (__fp16)W2[row*64 + col];
    o.h.y = (__fp16)W2[row*64 + col + 1];
    w2p[u] = o.v;
}

#define CONV_GROUP(cbase, OUT) \
    _Pragma("unroll") \
    for (int cg = 0; cg < 8; ++cg) { \
        const int c = (cbase) + cg; \
        const __fp16* base = w2s + ((cg*4)*64 + lane)*8; \
        half8_t wa0 = *(const half8_t*)(base); \
        half8_t wa1 = *(const half8_t*)(base + 64*8); \
        half8_t wb0 = *(const half8_t*)(base + 2*64*8); \
        half8_t wb1 = *(const half8_t*)(base + 3*64*8); \
        float4 bb0 = *(const float4*)(b2s + 32*c + quad*4); \
        float4 bb1 = *(const float4*)(b2s + 32*c + 16 + quad*4); \
        f32x4 acc0 = {bb0.x, bb0.y, bb0.z, bb0.w}; \
        acc0 = __builtin_amdgcn_mfma_f32_16x16x32_f16(wa0, h_lo, acc0, 0, 0, 0); \
        acc0 = __builtin_amdgcn_mfma_f32_16x16x32_f16(wa1, h_hi, acc0, 0, 0, 0); \
        f32x4 acc1 = {bb1.x, bb1.y, bb1.z, bb1.w}; \
        acc1 = __builtin_amdgcn_mfma_f32_16x16x32_f16(wb0, h_lo, acc1, 0, 0, 0); \
        acc1 = __builtin_amdgcn_mfma_f32_16x16x32_f16(wb1, h_hi, acc1, 0, 0, 0); \
        float p0 = 0.f, p1 = 0.f, p2 = 0.f; \
        _Pragma("unroll") \
        for (int r = 0; r < 4; ++r) { \
            half2_t rp = pk(acc0[r], acc1[r]); \
            p0 = fdot2(rp, t2[r][0], p0); \
            p1 = fdot2(rp, t2[r][1], p1); \
            p2 = fdot2(rp, t2[r][2], p2); \
        } \
        p0 += __shfl_xor(p0, 16); p0 += __shfl_xor(p0, 32); \
        p1 += __shfl_xor(p1, 16); p1 += __shfl_xor(p1, 32); \
        p2 += __shfl_xor(p2, 16); p2 += __shfl_xor(p2, 32); \
        OUT; \
    }

#define STAGE_W2(group) { \
    uint4* d4 = (uint4*)w2s; \
    _Pragma("unroll") \
    for (int i = 0; i < 8; ++i) d4[i*256 + tid] = w2p[(group)*2048 + i*256 + tid]; \
}

// ---- fused per-edge kernel: 256-thread blocks, 3-pass W2 LDS staging
// (32 KB/pass), 43 KB LDS -> 3 blocks/CU. Epilogue: softmax WITHOUT the
// per-node max pass (exp(s) is bounded ~e^2 here; ratio is identical), so
// attention reduces to fire-and-forget f32 atomics into num/den.
__global__ __launch_bounds__(256, 3)
void fused_kernel(const int* __restrict__ src, const int* __restrict__ dst,
                  const float* __restrict__ basis, const float* __restrict__ efeat,
                  const float* __restrict__ f,
                  const float* __restrict__ W1, const float* __restrict__ b1,
                  const uint4* __restrict__ w2p, const float* __restrict__ b2,
                  float* __restrict__ num, float* __restrict__ den)
{
    __shared__ __fp16 w2s[8*4*64*8];    // 32 KB, one 8-c-row group
    __shared__ float  w1s[64*32];       // 8 KB (xor-swizzled float4 granules)
    __shared__ float  b2s[768];         // 3 KB

    const int tid  = threadIdx.x;
    const int lane = tid & 63;
    const int wid  = tid >> 6;
    const int em   = lane & 15;
    const int quad = lane >> 4;
    const int e = (blockIdx.x * 4 + wid) * 16 + em;
    const int dn = dst[e];              // uniform across the 4 quads of an edge

    // ---- stage pass-1 (k rows c=0..7) + W1 (swizzled) + b2 ----
    STAGE_W2(0);
    {
        float4* w14 = (float4*)w1s;
        const float4* W14 = (const float4*)W1;
        w14[w1swz(tid)]       = W14[tid];
        w14[w1swz(256 + tid)] = W14[256 + tid];
        if (tid < 192) ((float4*)b2s)[tid] = ((const float4*)b2)[tid];
    }

    __syncthreads();

    // ---- Phase A: h = relu(x @ W1^T + b1), fp32 ----
    half8_t h_lo, h_hi;
    {
        float x[32];
        const float4* xv = (const float4*)(efeat + (size_t)e * 32);
        #pragma unroll
        for (int i = 0; i < 8; ++i) {
            float4 t = xv[i];
            x[4*i+0] = t.x; x[4*i+1] = t.y; x[4*i+2] = t.z; x[4*i+3] = t.w;
        }
        union { __fp16 h[8]; half8_t v; } lo, hi;
        #pragma unroll
        for (int t = 0; t < 8; ++t) {
            const int j0 = quad*8 + t;
            const int j1 = 32 + quad*8 + t;
            float a0 = b1[j0], a1 = b1[j1];
            const float4* r0 = (const float4*)w1s + j0*8;
            const float4* r1 = (const float4*)w1s + j1*8;
            #pragma unroll
            for (int l = 0; l < 8; ++l) {
                const int ip = l ^ quad;          // physical slot of logical l
                float4 wa = r0[ip];
                float4 wb = r1[ip];
                a0 = fmaf(wa.x, x[4*l+0], a0);
                a0 = fmaf(wa.y, x[4*l+1], a0);
                a0 = fmaf(wa.z, x[4*l+2], a0);
                a0 = fmaf(wa.w, x[4*l+3], a0);
                a1 = fmaf(wb.x, x[4*l+0], a1);
                a1 = fmaf(wb.y, x[4*l+1], a1);
                a1 = fmaf(wb.z, x[4*l+2], a1);
                a1 = fmaf(wb.w, x[4*l+3], a1);
            }
            lo.h[t] = (__fp16)fmaxf(a0, 0.0f);
            hi.h[t] = (__fp16)fmaxf(a1, 0.0f);
        }
        h_lo = lo.v; h_hi = hi.v;
    }

    // ---- Phase B: tmp2 quarter (mp = quad*4..+4), pairs (m', m'+16) ----
    half2_t t2[4][3];
    {
        float bas[18];
        const float2* bv = (const float2*)(basis + (size_t)e * 18);
        #pragma unroll
        for (int i = 0; i < 9; ++i) { float2 t = bv[i]; bas[2*i] = t.x; bas[2*i+1] = t.y; }
        const float* fp = f + (size_t)src[e] * 48 + quad*6;
        float fl[6], fh[6];
        #pragma unroll
        for (int i = 0; i < 3; ++i) {
            float2 a = *(const float2*)(fp + 2*i);      fl[2*i] = a.x; fl[2*i+1] = a.y;
            float2 b = *(const float2*)(fp + 24 + 2*i); fh[2*i] = b.x; fh[2*i+1] = b.y;
        }
        #pragma unroll
        for (int jj = 0; jj < 4; ++jj) {
            const int mr = (jj >> 1) * 3;
            const int rb = (jj & 1) * 3;
            #pragma unroll
            for (int d = 0; d < 3; ++d) {
                float lo = fmaf(fl[mr+0], bas[rb+d],
                           fmaf(fl[mr+1], bas[6+rb+d], fl[mr+2] * bas[12+rb+d]));
                float hi = fmaf(fh[mr+0], bas[rb+d],
                           fmaf(fh[mr+1], bas[6+rb+d], fh[mr+2] * bas[12+rb+d]));
                t2[jj][d] = pk(lo, hi);
            }
        }
    }

    // ---- pass 1: k rows (c = 0..7) ----
    float kreg[8][3];
    CONV_GROUP(0, { kreg[cg][0]=p0; kreg[cg][1]=p1; kreg[cg][2]=p2; });

    // ---- pass 2: q rows (c = 8..15) -> scores ----
    __syncthreads();
    STAGE_W2(1);
    __syncthreads();
    float sreg[4];
    CONV_GROUP(8, {
        float s_ = p0*kreg[cg][0] + p1*kreg[cg][1] + p2*kreg[cg][2];
        if ((cg & 1) == 0) sreg[cg>>1] = s_; else sreg[cg>>1] += s_;
    });

    // scores -> exp(leaky_relu(s*temp)); valid on ALL lanes (p's were
    // shfl-reduced across quads), no max subtraction needed (|s| ~ O(2)).
    float exv[4];
    #pragma unroll
    for (int hh = 0; hh < 4; ++hh) {
        float s = sreg[hh] * TEMP;
        s = (s > 0.0f) ? s : 0.2f * s;
        exv[hh] = __expf(s);
    }

    // ---- pass 3: v rows (c = 16..23) ----
    __syncthreads();
    STAGE_W2(2);
    __syncthreads();
    float vreg[8][3];
    CONV_GROUP(16, { vreg[cg][0]=p0; vreg[cg][1]=p1; vreg[cg][2]=p2; });

    // ---- epilogue: scatter-accumulate into num[n][24], den[n][4] ----
    // comp j = vreg[j/3][j%3]; head(j) = j/6; quad q owns j = q*8..q*8+7.
    float* nb = num + (size_t)dn * 24;
    if (quad == 0) {
        atomicAdd(nb+0, exv[0]*vreg[0][0]);
        atomicAdd(nb+1, exv[0]*vreg[0][1]);
        atomicAdd(nb+2, exv[0]*vreg[0][2]);
        atomicAdd(nb+3, exv[0]*vreg[1][0]);
        atomicAdd(nb+4, exv[0]*vreg[1][1]);
        atomicAdd(nb+5, exv[0]*vreg[1][2]);
        atomicAdd(nb+6, exv[1]*vreg[2][0]);
        atomicAdd(nb+7, exv[1]*vreg[2][1]);
    } else if (quad == 1) {
        atomicAdd(nb+8,  exv[1]*vreg[2][2]);
        atomicAdd(nb+9,  exv[1]*vreg[3][0]);
        atomicAdd(nb+10, exv[1]*vreg[3][1]);
        atomicAdd(nb+11, exv[1]*vreg[3][2]);
        atomicAdd(nb+12, exv[2]*vreg[4][0]);
        atomicAdd(nb+13, exv[2]*vreg[4][1]);
        atomicAdd(nb+14, exv[2]*vreg[4][2]);
        atomicAdd(nb+15, exv[2]*vreg[5][0]);
    } else if (quad == 2) {
        atomicAdd(nb+16, exv[2]*vreg[5][1]);
        atomicAdd(nb+17, exv[2]*vreg[5][2]);
        atomicAdd(nb+18, exv[3]*vreg[6][0]);
        atomicAdd(nb+19, exv[3]*vreg[6][1]);
        atomicAdd(nb+20, exv[3]*vreg[6][2]);
        atomicAdd(nb+21, exv[3]*vreg[7][0]);
        atomicAdd(nb+22, exv[3]*vreg[7][1]);
        atomicAdd(nb+23, exv[3]*vreg[7][2]);
    } else {
        float* db = den + (size_t)dn * 4;
        atomicAdd(db+0, exv[0]);
        atomicAdd(db+1, exv[1]);
        atomicAdd(db+2, exv[2]);
        atomicAdd(db+3, exv[3]);
    }
}

// ---- finalize: out = num / den (per node, per component) ----
__global__ __launch_bounds__(256)
void finalize_kernel(const float* __restrict__ num, const float* __restrict__ den,
                     float* __restrict__ out)
{
    int t = blockIdx.x * 256 + threadIdx.x;
    if (t >= N_NODES * 24) return;
    int n = t / 24;
    int j = t - n * 24;
    int h = j / 6;
    float d = den[n*4 + h];
    out[t] = (d > 0.f) ? num[t] / d : 0.f;
}

extern "C" void kernel_launch(void* const* d_in, const int* in_sizes, int n_in,
                              void* d_out, int out_size, void* d_ws, size_t ws_size,
                              hipStream_t stream)
{
    const int*   src   = (const int*)d_in[0];
    const int*   dst   = (const int*)d_in[1];
    const float* basis = (const float*)d_in[2];
    const float* ef    = (const float*)d_in[3];
    const float* f     = (const float*)d_in[4];
    const float* W1    = (const float*)d_in[5];
    const float* b1    = (const float*)d_in[6];
    const float* W2    = (const float*)d_in[7];
    const float* b2    = (const float*)d_in[8];
    float* out = (float*)d_out;

    float*    num = (float*)d_ws;                       // N*24 f32 (0.96 MB)
    float*    den = num + (size_t)N_NODES * 24;         // N*4  f32 (0.16 MB)
    unsigned* w2p = (unsigned*)(den + (size_t)N_NODES * 4); // 24576 u32 (96 KB)

    prep_kernel<<<96, 256, 0, stream>>>(W2, w2p, (float4*)num);

    fused_kernel<<<E_EDGES / 64, 256, 0, stream>>>(src, dst, basis, ef, f,
                                                   W1, b1, (const uint4*)w2p, b2,
                                                   num, den);

    finalize_kernel<<<(N_NODES * 24 + 255) / 256, 256, 0, stream>>>(num, den, out);
}

// Round 3
// 149.696 us; speedup vs baseline: 2.2939x; 2.2939x over previous
//
#include <hip/hip_runtime.h>

#define E_EDGES 160000
#define N_NODES 10000
#define SLOTS   32      // per-node bucket capacity; overflow falls back to atomics

// 24^(-0.5)
#define TEMP 0.20412414523193154f

typedef __fp16 half2_t __attribute__((ext_vector_type(2)));
typedef __fp16 half8_t __attribute__((ext_vector_type(8)));
typedef float f32x4 __attribute__((ext_vector_type(4)));

__device__ __forceinline__ float fdot2(half2_t a, half2_t b, float c) {
#if __has_builtin(__builtin_amdgcn_fdot2)
    return __builtin_amdgcn_fdot2(a, b, c, false);
#else
    return fmaf((float)a.x, (float)b.x, fmaf((float)a.y, (float)b.y, c));
#endif
}
__device__ __forceinline__ half2_t pk(float a, float b) {
    return __builtin_amdgcn_cvt_pkrtz(a, b);
}

// W1 LDS swizzle: float4-granule XOR keyed by (row>>3)&3 so the 4 quads
// (rows 8 apart) hit disjoint 16B slots -> no 4-way bank conflict.
// (R2-verified: SQ_LDS_BANK_CONFLICT 5.12M -> 0, results bit-correct.)
__device__ __forceinline__ int w1swz(int u) {
    return (u & ~7) | ((u & 7) ^ ((u >> 6) & 3));
}

// prep: W2 [768][64] f32 -> f16 fragment order; zero cnt + num/den.
__global__ __launch_bounds__(256)
void prep_kernel(const float* __restrict__ W2, unsigned* __restrict__ w2p,
                 int* __restrict__ cnt, float4* __restrict__ zbuf)
{
    int u = blockIdx.x * blockDim.x + threadIdx.x;   // u < 24576
    if (u < N_NODES) cnt[u] = 0;
    // zero num (N*24) + den (N*4) = 70000 float4 (contiguous)
    #pragma unroll
    for (int i = 0; i < 3; ++i) {
        int z = u + i * 24576;
        if (z < (N_NODES * 28) / 4) zbuf[z] = make_float4(0.f, 0.f, 0.f, 0.f);
    }
    int tp    = u & 3;
    int lane  = (u >> 2) & 63;
    int piece = (u >> 8) & 3;
    int c     = u >> 10;
    int em = lane & 15, quad = lane >> 4;
    int row = 32*c + ((piece >> 1) << 4) + em;
    int col = ((piece & 1) << 5) + quad*8 + 2*tp;
    union { half2_t h; unsigned v; } o;
    o.h.x = (__fp16)W2[row*64 + col];
    o.h.y = (__fp16)W2[row*64 + col + 1];
    w2p[u] = o.v;
}

#define CONV_GROUP(cbase, OUT) \
    _Pragma("unroll") \
    for (int cg = 0; cg < 8; ++cg) { \
        const int c = (cbase) + cg; \
        const __fp16* base = w2s + ((cg*4)*64 + lane)*8; \
        half8_t wa0 = *(const half8_t*)(base); \
        half8_t wa1 = *(const half8_t*)(base + 64*8); \
        half8_t wb0 = *(const half8_t*)(base + 2*64*8); \
        half8_t wb1 = *(const half8_t*)(base + 3*64*8); \
        float4 bb0 = *(const float4*)(b2s + 32*c + quad*4); \
        float4 bb1 = *(const float4*)(b2s + 32*c + 16 + quad*4); \
        f32x4 acc0 = {bb0.x, bb0.y, bb0.z, bb0.w}; \
        acc0 = __builtin_amdgcn_mfma_f32_16x16x32_f16(wa0, h_lo, acc0, 0, 0, 0); \
        acc0 = __builtin_amdgcn_mfma_f32_16x16x32_f16(wa1, h_hi, acc0, 0, 0, 0); \
        f32x4 acc1 = {bb1.x, bb1.y, bb1.z, bb1.w}; \
        acc1 = __builtin_amdgcn_mfma_f32_16x16x32_f16(wb0, h_lo, acc1, 0, 0, 0); \
        acc1 = __builtin_amdgcn_mfma_f32_16x16x32_f16(wb1, h_hi, acc1, 0, 0, 0); \
        float p0 = 0.f, p1 = 0.f, p2 = 0.f; \
        _Pragma("unroll") \
        for (int r = 0; r < 4; ++r) { \
            half2_t rp = pk(acc0[r], acc1[r]); \
            p0 = fdot2(rp, t2[r][0], p0); \
            p1 = fdot2(rp, t2[r][1], p1); \
            p2 = fdot2(rp, t2[r][2], p2); \
        } \
        p0 += __shfl_xor(p0, 16); p0 += __shfl_xor(p0, 32); \
        p1 += __shfl_xor(p1, 16); p1 += __shfl_xor(p1, 32); \
        p2 += __shfl_xor(p2, 16); p2 += __shfl_xor(p2, 32); \
        OUT; \
    }

#define STAGE_W2(group) { \
    uint4* d4 = (uint4*)w2s; \
    _Pragma("unroll") \
    for (int i = 0; i < 8; ++i) d4[i*256 + tid] = w2p[(group)*2048 + i*256 + tid]; \
}

// ---- fused per-edge kernel: 256-thread blocks, 3-pass W2 LDS staging
// (32 KB/pass), 43 KB LDS -> 3 blocks/CU. Epilogue: no-max softmax
// (R2-verified numerically); 64 B bucket record per edge written with four
// plain 16 B stores (one per quad): [0:48) 24*fp16 v, [48:64) 4*f32 exp(s).
// Rare bucket overflow (p >= SLOTS) falls back to atomic num/den.
__global__ __launch_bounds__(256, 3)
void fused_kernel(const int* __restrict__ src, const int* __restrict__ dst,
                  const float* __restrict__ basis, const float* __restrict__ efeat,
                  const float* __restrict__ f,
                  const float* __restrict__ W1, const float* __restrict__ b1,
                  const uint4* __restrict__ w2p, const float* __restrict__ b2,
                  unsigned char* __restrict__ bkt, int* __restrict__ cnt,
                  float* __restrict__ num, float* __restrict__ den)
{
    __shared__ __fp16 w2s[8*4*64*8];    // 32 KB, one 8-c-row group
    __shared__ float  w1s[64*32];       // 8 KB (xor-swizzled float4 granules)
    __shared__ float  b2s[768];         // 3 KB

    const int tid  = threadIdx.x;
    const int lane = tid & 63;
    const int wid  = tid >> 6;
    const int em   = lane & 15;
    const int quad = lane >> 4;
    const int e = (blockIdx.x * 4 + wid) * 16 + em;

    // ---- stage pass-1 (k rows c=0..7) + W1 (swizzled) + b2 ----
    STAGE_W2(0);
    {
        float4* w14 = (float4*)w1s;
        const float4* W14 = (const float4*)W1;
        w14[w1swz(tid)]       = W14[tid];
        w14[w1swz(256 + tid)] = W14[256 + tid];
        if (tid < 192) ((float4*)b2s)[tid] = ((const float4*)b2)[tid];
    }

    // ---- bucket placement: one atomic per edge, slot broadcast to all quads ----
    int p_slot = 0, dn0 = 0;
    if (quad == 0) {
        dn0 = dst[e];
        p_slot = atomicAdd(&cnt[dn0], 1);
    }
    const int pb  = __shfl(p_slot, em);
    const int dnb = __shfl(dn0, em);

    __syncthreads();

    // ---- Phase A: h = relu(x @ W1^T + b1), fp32 ----
    half8_t h_lo, h_hi;
    {
        float x[32];
        const float4* xv = (const float4*)(efeat + (size_t)e * 32);
        #pragma unroll
        for (int i = 0; i < 8; ++i) {
            float4 t = xv[i];
            x[4*i+0] = t.x; x[4*i+1] = t.y; x[4*i+2] = t.z; x[4*i+3] = t.w;
        }
        union { __fp16 h[8]; half8_t v; } lo, hi;
        #pragma unroll
        for (int t = 0; t < 8; ++t) {
            const int j0 = quad*8 + t;
            const int j1 = 32 + quad*8 + t;
            float a0 = b1[j0], a1 = b1[j1];
            const float4* r0 = (const float4*)w1s + j0*8;
            const float4* r1 = (const float4*)w1s + j1*8;
            #pragma unroll
            for (int l = 0; l < 8; ++l) {
                const int ip = l ^ quad;          // physical slot of logical l
                float4 wa = r0[ip];
                float4 wb = r1[ip];
                a0 = fmaf(wa.x, x[4*l+0], a0);
                a0 = fmaf(wa.y, x[4*l+1], a0);
                a0 = fmaf(wa.z, x[4*l+2], a0);
                a0 = fmaf(wa.w, x[4*l+3], a0);
                a1 = fmaf(wb.x, x[4*l+0], a1);
                a1 = fmaf(wb.y, x[4*l+1], a1);
                a1 = fmaf(wb.z, x[4*l+2], a1);
                a1 = fmaf(wb.w, x[4*l+3], a1);
            }
            lo.h[t] = (__fp16)fmaxf(a0, 0.0f);
            hi.h[t] = (__fp16)fmaxf(a1, 0.0f);
        }
        h_lo = lo.v; h_hi = hi.v;
    }

    // ---- Phase B: tmp2 quarter (mp = quad*4..+4), pairs (m', m'+16) ----
    half2_t t2[4][3];
    {
        float bas[18];
        const float2* bv = (const float2*)(basis + (size_t)e * 18);
        #pragma unroll
        for (int i = 0; i < 9; ++i) { float2 t = bv[i]; bas[2*i] = t.x; bas[2*i+1] = t.y; }
        const float* fp = f + (size_t)src[e] * 48 + quad*6;
        float fl[6], fh[6];
        #pragma unroll
        for (int i = 0; i < 3; ++i) {
            float2 a = *(const float2*)(fp + 2*i);      fl[2*i] = a.x; fl[2*i+1] = a.y;
            float2 b = *(const float2*)(fp + 24 + 2*i); fh[2*i] = b.x; fh[2*i+1] = b.y;
        }
        #pragma unroll
        for (int jj = 0; jj < 4; ++jj) {
            const int mr = (jj >> 1) * 3;
            const int rb = (jj & 1) * 3;
            #pragma unroll
            for (int d = 0; d < 3; ++d) {
                float lo = fmaf(fl[mr+0], bas[rb+d],
                           fmaf(fl[mr+1], bas[6+rb+d], fl[mr+2] * bas[12+rb+d]));
                float hi = fmaf(fh[mr+0], bas[rb+d],
                           fmaf(fh[mr+1], bas[6+rb+d], fh[mr+2] * bas[12+rb+d]));
                t2[jj][d] = pk(lo, hi);
            }
        }
    }

    // ---- pass 1: k rows (c = 0..7) ----
    float kreg[8][3];
    CONV_GROUP(0, { kreg[cg][0]=p0; kreg[cg][1]=p1; kreg[cg][2]=p2; });

    // ---- pass 2: q rows (c = 8..15) -> scores ----
    __syncthreads();
    STAGE_W2(1);
    __syncthreads();
    float sreg[4];
    CONV_GROUP(8, {
        float s_ = p0*kreg[cg][0] + p1*kreg[cg][1] + p2*kreg[cg][2];
        if ((cg & 1) == 0) sreg[cg>>1] = s_; else sreg[cg>>1] += s_;
    });

    // exp(leaky_relu(s*temp)) on all lanes; no max subtraction (R2-verified).
    float exv[4];
    #pragma unroll
    for (int hh = 0; hh < 4; ++hh) {
        float s = sreg[hh] * TEMP;
        s = (s > 0.0f) ? s : 0.2f * s;
        exv[hh] = __expf(s);
    }

    // ---- pass 3: v rows (c = 16..23) ----
    __syncthreads();
    STAGE_W2(2);
    __syncthreads();
    float vreg[8][3];
    CONV_GROUP(16, { vreg[cg][0]=p0; vreg[cg][1]=p1; vreg[cg][2]=p2; });

    // ---- epilogue ----
    if (pb < SLOTS) {
        unsigned char* rec = bkt + ((size_t)dnb * SLOTS + pb) * 64;
        if (quad == 3) {
            *(float4*)(rec + 48) = make_float4(exv[0], exv[1], exv[2], exv[3]);
        } else {
            union { half2_t h2[4]; uint4 u; } pv;
            if (quad == 0) {
                pv.h2[0] = pk(vreg[0][0], vreg[0][1]);
                pv.h2[1] = pk(vreg[0][2], vreg[1][0]);
                pv.h2[2] = pk(vreg[1][1], vreg[1][2]);
                pv.h2[3] = pk(vreg[2][0], vreg[2][1]);
            } else if (quad == 1) {
                pv.h2[0] = pk(vreg[2][2], vreg[3][0]);
                pv.h2[1] = pk(vreg[3][1], vreg[3][2]);
                pv.h2[2] = pk(vreg[4][0], vreg[4][1]);
                pv.h2[3] = pk(vreg[4][2], vreg[5][0]);
            } else {
                pv.h2[0] = pk(vreg[5][1], vreg[5][2]);
                pv.h2[1] = pk(vreg[6][0], vreg[6][1]);
                pv.h2[2] = pk(vreg[6][2], vreg[7][0]);
                pv.h2[3] = pk(vreg[7][1], vreg[7][2]);
            }
            *(uint4*)(rec + quad*16) = pv.u;
        }
    } else {
        // rare overflow: atomic fallback (few edges at most)
        float* nb = num + (size_t)dnb * 24;
        if (quad == 0) {
            atomicAdd(nb+0, exv[0]*vreg[0][0]); atomicAdd(nb+1, exv[0]*vreg[0][1]);
            atomicAdd(nb+2, exv[0]*vreg[0][2]); atomicAdd(nb+3, exv[0]*vreg[1][0]);
            atomicAdd(nb+4, exv[0]*vreg[1][1]); atomicAdd(nb+5, exv[0]*vreg[1][2]);
            atomicAdd(nb+6, exv[1]*vreg[2][0]); atomicAdd(nb+7, exv[1]*vreg[2][1]);
        } else if (quad == 1) {
            atomicAdd(nb+8,  exv[1]*vreg[2][2]); atomicAdd(nb+9,  exv[1]*vreg[3][0]);
            atomicAdd(nb+10, exv[1]*vreg[3][1]); atomicAdd(nb+11, exv[1]*vreg[3][2]);
            atomicAdd(nb+12, exv[2]*vreg[4][0]); atomicAdd(nb+13, exv[2]*vreg[4][1]);
            atomicAdd(nb+14, exv[2]*vreg[4][2]); atomicAdd(nb+15, exv[2]*vreg[5][0]);
        } else if (quad == 2) {
            atomicAdd(nb+16, exv[2]*vreg[5][1]); atomicAdd(nb+17, exv[2]*vreg[5][2]);
            atomicAdd(nb+18, exv[3]*vreg[6][0]); atomicAdd(nb+19, exv[3]*vreg[6][1]);
            atomicAdd(nb+20, exv[3]*vreg[6][2]); atomicAdd(nb+21, exv[3]*vreg[7][0]);
            atomicAdd(nb+22, exv[3]*vreg[7][1]); atomicAdd(nb+23, exv[3]*vreg[7][2]);
        } else {
            float* db = den + (size_t)dnb * 4;
            atomicAdd(db+0, exv[0]); atomicAdd(db+1, exv[1]);
            atomicAdd(db+2, exv[2]); atomicAdd(db+3, exv[3]);
        }
    }
}

// ---- gather: one wave per node; contiguous 64 B records, no max phase ----
__global__ __launch_bounds__(256)
void gather_kernel(const int* __restrict__ cnt, const unsigned char* __restrict__ bkt,
                   const float* __restrict__ num, const float* __restrict__ den,
                   float* __restrict__ out)
{
    const int lane = threadIdx.x & 63;
    const int wid  = threadIdx.x >> 6;
    const int n = blockIdx.x * 4 + wid;
    if (n >= N_NODES) return;
    int deg = cnt[n];
    if (deg > SLOTS) deg = SLOTS;
    const unsigned char* rec = bkt + (size_t)n * SLOTS * 64;

    const int j = lane & 31;            // output component (j < 24)
    const int half = lane >> 5;         // slot-range split
    const int hd = (j < 24) ? (j / 6) : 0;

    float acc = 0.f, dn_ = 0.f;
    if (j < 24 && half == 0) {          // merge rare overflow contributions
        acc = num[n*24 + j];
        dn_ = den[n*4 + hd];
    }
    if (j < 24) {
        #pragma unroll 2
        for (int i = half; i < deg; i += 2) {
            const unsigned char* r = rec + (size_t)i * 64;
            float ex = *(const float*)(r + 48 + hd*4);
            float v  = (float)*(const __fp16*)(r + j*2);
            dn_ += ex;
            acc = fmaf(ex, v, acc);
        }
    }
    acc += __shfl_xor(acc, 32);
    dn_ += __shfl_xor(dn_, 32);
    if (half == 0 && j < 24) {
        out[n*24 + j] = (dn_ > 0.f) ? (acc / dn_) : 0.f;
    }
}

extern "C" void kernel_launch(void* const* d_in, const int* in_sizes, int n_in,
                              void* d_out, int out_size, void* d_ws, size_t ws_size,
                              hipStream_t stream)
{
    const int*   src   = (const int*)d_in[0];
    const int*   dst   = (const int*)d_in[1];
    const float* basis = (const float*)d_in[2];
    const float* ef    = (const float*)d_in[3];
    const float* f     = (const float*)d_in[4];
    const float* W1    = (const float*)d_in[5];
    const float* b1    = (const float*)d_in[6];
    const float* W2    = (const float*)d_in[7];
    const float* b2    = (const float*)d_in[8];
    float* out = (float*)d_out;

    // workspace (~21.7 MB total, matches previously-proven budget)
    unsigned char* bkt = (unsigned char*)d_ws;                      // N*SLOTS*64 B (20.48 MB)
    float* num = (float*)(bkt + (size_t)N_NODES * SLOTS * 64);      // N*24 f32 (0.96 MB)
    float* den = num + (size_t)N_NODES * 24;                        // N*4 f32 (0.16 MB)
    unsigned* w2p = (unsigned*)(den + (size_t)N_NODES * 4);         // 24576 u32 (96 KB)
    int* cnt = (int*)(w2p + 24576);                                 // N int (40 KB)

    prep_kernel<<<96, 256, 0, stream>>>(W2, w2p, cnt, (float4*)num);

    fused_kernel<<<E_EDGES / 64, 256, 0, stream>>>(src, dst, basis, ef, f,
                                                   W1, b1, (const uint4*)w2p, b2,
                                                   bkt, cnt, num, den);

    gather_kernel<<<(N_NODES + 3) / 4, 256, 0, stream>>>(cnt, bkt, num, den, out);
}